// Round 2
// baseline (3333.015 us; speedup 1.0000x reference)
//
#include <hip/hip_runtime.h>

#define NF 64
#define NC 40

// ---------- setup kernels (run once per call) ----------

__global__ void k_deg(const int* __restrict__ row, int* __restrict__ deg_cnt, int E) {
    int stride = gridDim.x * blockDim.x;
    for (int e = blockIdx.x * blockDim.x + threadIdx.x; e < E; e += stride)
        atomicAdd(&deg_cnt[row[e]], 1);
}

__global__ void k_node(const float* __restrict__ x, const int* __restrict__ y,
                       const int* __restrict__ mask, int* __restrict__ ylab,
                       int* __restrict__ cls_cnt, float* __restrict__ mean_sum, int N) {
    __shared__ float lmean[NF];
    __shared__ int   lcls[NC];
    int t = threadIdx.x;
    if (t < NF) lmean[t] = 0.f;
    if (t < NC) lcls[t]  = 0;
    __syncthreads();
    int stride = gridDim.x * blockDim.x;
    // column sums of x (stride is a multiple of 64 so each thread stays on one column)
    float acc = 0.f;
    long total = (long)N * NF;
    for (long i = blockIdx.x * blockDim.x + t; i < total; i += stride)
        acc += x[i];
    atomicAdd(&lmean[t & (NF - 1)], acc);
    // labels + per-class counts
    for (int i = blockIdx.x * blockDim.x + t; i < N; i += stride) {
        int lab = (mask[i] > 0) ? y[i] : -1;
        ylab[i] = lab;
        if (lab >= 0) atomicAdd(&lcls[lab], 1);
    }
    __syncthreads();
    if (t < NF) atomicAdd(&mean_sum[t], lmean[t]);
    if (t < NC) atomicAdd(&cls_cnt[t], lcls[t]);
}

__global__ void k_scan(const int* __restrict__ deg_cnt, int* __restrict__ row_ptr,
                       float* __restrict__ inv_deg, const int* __restrict__ cls_cnt,
                       int* __restrict__ cls_ptr, float* __restrict__ inv_cnt,
                       const float* __restrict__ mean_sum, float* __restrict__ meanv,
                       int N) {
    __shared__ int lds[1024];
    int t = threadIdx.x;
    int chunk = (N + 1023) >> 10;
    int lo = t * chunk;
    int hi = lo + chunk; if (hi > N) hi = N; if (lo > N) lo = N;
    int s = 0;
    for (int i = lo; i < hi; ++i) s += deg_cnt[i];
    lds[t] = s;
    __syncthreads();
    for (int off = 1; off < 1024; off <<= 1) {
        int v = (t >= off) ? lds[t - off] : 0;
        __syncthreads();
        lds[t] += v;
        __syncthreads();
    }
    int base = lds[t] - s;  // exclusive prefix
    for (int i = lo; i < hi; ++i) {
        int d = deg_cnt[i];
        row_ptr[i] = base;
        inv_deg[i] = 1.f / (float)(d + 1);
        base += d;
    }
    if (t == 1023) row_ptr[N] = lds[1023];
    if (t < NF) meanv[t] = mean_sum[t] * (1.f / (float)N);
    if (t == 0) {
        int s2 = 0;
        for (int c = 0; c < NC; ++c) {
            cls_ptr[c] = s2;
            int cc = cls_cnt[c];
            s2 += cc;
            inv_cnt[c] = 1.f / ((float)cc + 1e-8f);
        }
        cls_ptr[NC] = s2;
    }
}

// deg_cnt is consumed as a countdown counter here (reaches 0; re-zeroed by
// the memset at the start of every call before k_deg rebuilds it).
__global__ void k_fill(const int* __restrict__ row, const int* __restrict__ col,
                       const int* __restrict__ row_ptr, int* __restrict__ deg_cnt,
                       int* __restrict__ csr_col, const int* __restrict__ ylab,
                       const int* __restrict__ cls_ptr, int* __restrict__ cls_fill,
                       int* __restrict__ cls_nodes, int N, int E) {
    int stride = gridDim.x * blockDim.x;
    for (int e = blockIdx.x * blockDim.x + threadIdx.x; e < E; e += stride) {
        int r = row[e];
        int d = atomicSub(&deg_cnt[r], 1);       // unique slot per edge
        csr_col[row_ptr[r] + d - 1] = col[e];
    }
    for (int i = blockIdx.x * blockDim.x + threadIdx.x; i < N; i += stride) {
        int lab = ylab[i];
        if (lab >= 0) {
            int pos = cls_ptr[lab] + atomicAdd(&cls_fill[lab], 1);
            cls_nodes[pos] = i;
        }
    }
}

__global__ void k_init(const float* __restrict__ x, const float* __restrict__ meanv,
                       float* __restrict__ vinit, int N) {
    long total = (long)N * NF;
    long stride = (long)gridDim.x * blockDim.x;
    for (long i = blockIdx.x * blockDim.x + threadIdx.x; i < total; i += stride)
        vinit[i] = x[i] - meanv[(int)(i & (NF - 1))];
}

// ---------- per-iteration kernels ----------

// class sums of v over training nodes: yTv[c][f] += sum_{i in class c} v[i][f]
__global__ void __launch_bounds__(256) k_accum(const float* __restrict__ v,
                                               const int* __restrict__ cls_ptr,
                                               const int* __restrict__ cls_nodes,
                                               float* __restrict__ yTv) {
    __shared__ float red[4][NF];
    int c = blockIdx.x;               // class
    int lane = threadIdx.x & 63;
    int w = threadIdx.x >> 6;         // 0..3
    int W = blockIdx.y * 4 + w;       // 0..63 waves per class
    int cs = cls_ptr[c], ce = cls_ptr[c + 1];
    float acc = 0.f;
    for (int p = cs + W; p < ce; p += 64) {
        int node = cls_nodes[p];
        acc += v[(long)node * NF + lane];
    }
    red[w][lane] = acc;
    __syncthreads();
    if (w == 0) {
        float s = red[0][lane] + red[1][lane] + red[2][lane] + red[3][lane];
        atomicAdd(&yTv[c * NF + lane], s);
    }
}

// v_new[i] = 0.45*inv_deg[i]*(v[i] + sum_{j in N(i)} v[j]) + 0.05*p2[i] + 0.5*(x[i]-mean)
__global__ void __launch_bounds__(256) k_combine(
        const float* __restrict__ v, float* __restrict__ vn,
        const float* __restrict__ x, const float* __restrict__ meanv,
        const float* __restrict__ inv_deg,
        const int* __restrict__ row_ptr, const int* __restrict__ csr_col,
        const int* __restrict__ ylab, const float* __restrict__ yTv_cur,
        const float* __restrict__ inv_cnt, float* __restrict__ yTv_next_zero, int N) {
    int lane = threadIdx.x & 63;
    int w = threadIdx.x >> 6;
    int i = blockIdx.x * 4 + w;
    if (blockIdx.x == 0) {  // zero next iteration's yTv buffer
        for (int j = threadIdx.x; j < NC * NF; j += 256) yTv_next_zero[j] = 0.f;
    }
    if (i >= N) return;
    int s = row_ptr[i], e = row_ptr[i + 1];
    float acc0 = v[(long)i * NF + lane];
    float acc1 = 0.f;
    int p = s;
    for (; p + 1 < e; p += 2) {
        int c0 = csr_col[p], c1 = csr_col[p + 1];
        acc0 += v[(long)c0 * NF + lane];
        acc1 += v[(long)c1 * NF + lane];
    }
    if (p < e) acc0 += v[(long)csr_col[p] * NF + lane];
    float p1 = inv_deg[i] * (acc0 + acc1);
    int lab = ylab[i];
    float p2 = (lab >= 0) ? yTv_cur[lab * NF + lane] * inv_cnt[lab] : 0.f;
    float base = x[(long)i * NF + lane] - meanv[lane];
    vn[(long)i * NF + lane] = 0.45f * p1 + 0.05f * p2 + 0.5f * base;
}

// out = v @ W + bias  (in-place safe: each wave loads its own row to a register
// before storing; shfl operates on registers, not memory)
__global__ void __launch_bounds__(256) k_out(const float* __restrict__ v,
                                             const float* __restrict__ Wm,
                                             const float* __restrict__ bias,
                                             float* __restrict__ out, int N) {
    __shared__ float Wl[NF * NF];
    for (int j = threadIdx.x; j < NF * NF; j += 256) Wl[j] = Wm[j];
    __syncthreads();
    int lane = threadIdx.x & 63;
    int w = threadIdx.x >> 6;
    int i = blockIdx.x * 4 + w;
    if (i >= N) return;
    float vr = v[(long)i * NF + lane];
    float acc = bias[lane];
#pragma unroll
    for (int k = 0; k < NF; ++k)
        acc += __shfl(vr, k, 64) * Wl[k * NF + lane];
    out[(long)i * NF + lane] = acc;
}

// ---------- launcher ----------

extern "C" void kernel_launch(void* const* d_in, const int* in_sizes, int n_in,
                              void* d_out, int out_size, void* d_ws, size_t ws_size,
                              hipStream_t stream) {
    const float* x      = (const float*)d_in[0];
    const float* weight = (const float*)d_in[1];
    const float* bias   = (const float*)d_in[2];
    const int*   row    = (const int*)d_in[3];
    const int*   col    = (const int*)d_in[4];
    const int*   y      = (const int*)d_in[5];
    const int*   mask   = (const int*)d_in[6];
    int N = in_sizes[0] / NF;
    int E = in_sizes[3];

    // Workspace layout (~17.2 MB total). Iteration-phase writes at the lowest
    // offsets; setup-only buffers at the tail. d_out doubles as one side of
    // the v ping-pong (50 steps starting at d_out -> final v back in d_out).
    char* ws = (char*)d_ws;
    size_t off = 0;
    auto alloc = [&](size_t bytes) -> void* {
        void* p = ws + off;
        off = (off + bytes + 255) & ~(size_t)255;
        return p;
    };
    float* v0        = (float*)alloc((size_t)N * NF * 4);   // 12.8 MB
    // zero region (contiguous, one memset per call)
    char*  zbase     = ws + off;
    float* yTv0      = (float*)alloc(NC * NF * 4);
    float* yTv1      = (float*)alloc(NC * NF * 4);
    int*   deg_cnt   = (int*)  alloc((size_t)N * 4);
    int*   cls_cnt   = (int*)  alloc(NC * 4);
    int*   cls_fill  = (int*)  alloc(NC * 4);
    float* mean_sum  = (float*)alloc(NF * 4);
    size_t zbytes = (size_t)((ws + off) - zbase);
    // setup-written, iteration-read
    float* meanv     = (float*)alloc(NF * 4);
    float* inv_deg   = (float*)alloc((size_t)N * 4);
    int*   row_ptr   = (int*)  alloc((size_t)(N + 1) * 4);
    int*   cls_ptr   = (int*)  alloc((NC + 1) * 4);
    float* inv_cnt   = (float*)alloc(NC * 4);
    int*   ylab      = (int*)  alloc((size_t)N * 4);
    int*   cls_nodes = (int*)  alloc((size_t)N * 4);
    int*   csr_col   = (int*)  alloc((size_t)E * 4);        // 3.2 MB

    float* vout = (float*)d_out;   // ping-pong partner of v0

    hipMemsetAsync(zbase, 0, zbytes, stream);

    k_deg <<<1024, 256, 0, stream>>>(row, deg_cnt, E);
    k_node<<<128, 256, 0, stream>>>(x, y, mask, ylab, cls_cnt, mean_sum, N);
    k_scan<<<1, 1024, 0, stream>>>(deg_cnt, row_ptr, inv_deg, cls_cnt, cls_ptr,
                                   inv_cnt, mean_sum, meanv, N);
    k_fill<<<1024, 256, 0, stream>>>(row, col, row_ptr, deg_cnt, csr_col,
                                     ylab, cls_ptr, cls_fill, cls_nodes, N, E);
    k_init<<<2048, 256, 0, stream>>>(x, meanv, vout, N);   // v_0 = xc in d_out

    int nblk = (N + 3) / 4;
    for (int t = 0; t < 50; ++t) {
        const float* vc = (t & 1) ? v0   : vout;
        float*       vn = (t & 1) ? vout : v0;
        float* yv_cur = (t & 1) ? yTv1 : yTv0;
        float* yv_nxt = (t & 1) ? yTv0 : yTv1;
        k_accum<<<dim3(NC, 16), 256, 0, stream>>>(vc, cls_ptr, cls_nodes, yv_cur);
        k_combine<<<nblk, 256, 0, stream>>>(vc, vn, x, meanv, inv_deg, row_ptr,
                                            csr_col, ylab, yv_cur, inv_cnt, yv_nxt, N);
    }
    // after 50 iters (even count), final v is back in d_out
    k_out<<<nblk, 256, 0, stream>>>(vout, weight, bias, (float*)d_out, N);
}

// Round 3
// 2193.673 us; speedup vs baseline: 1.5194x; 1.5194x over previous
//
#include <hip/hip_runtime.h>

#define NF 64
#define NC 40

// ---------- setup kernels (run once per call) ----------

__global__ void k_deg(const int* __restrict__ row, int* __restrict__ deg_cnt, int E) {
    int stride = gridDim.x * blockDim.x;
    for (int e = blockIdx.x * blockDim.x + threadIdx.x; e < E; e += stride)
        atomicAdd(&deg_cnt[row[e]], 1);
}

__global__ void k_node(const float* __restrict__ x, const int* __restrict__ y,
                       const int* __restrict__ mask, int* __restrict__ ylab,
                       int* __restrict__ cls_cnt, float* __restrict__ mean_sum, int N) {
    __shared__ float lmean[NF];
    __shared__ int   lcls[NC];
    int t = threadIdx.x;
    if (t < NF) lmean[t] = 0.f;
    if (t < NC) lcls[t]  = 0;
    __syncthreads();
    int stride = gridDim.x * blockDim.x;
    float acc = 0.f;
    long total = (long)N * NF;
    for (long i = blockIdx.x * blockDim.x + t; i < total; i += stride)
        acc += x[i];
    atomicAdd(&lmean[t & (NF - 1)], acc);
    for (int i = blockIdx.x * blockDim.x + t; i < N; i += stride) {
        int lab = (mask[i] > 0) ? y[i] : -1;
        ylab[i] = lab;
        if (lab >= 0) atomicAdd(&lcls[lab], 1);
    }
    __syncthreads();
    if (t < NF) atomicAdd(&mean_sum[t], lmean[t]);
    if (t < NC) atomicAdd(&cls_cnt[t], lcls[t]);
}

// hierarchical scan of deg_cnt (N assumed %4==0; N=50000 -> n4=12500)
__global__ void __launch_bounds__(256) k_blocksum(const int* __restrict__ deg_cnt,
                                                  int* __restrict__ bsum, int n4) {
    __shared__ int red[256];
    int idx4 = blockIdx.x * 256 + threadIdx.x;
    int s = 0;
    if (idx4 < n4) {
        int4 d = ((const int4*)deg_cnt)[idx4];
        s = d.x + d.y + d.z + d.w;
    }
    red[threadIdx.x] = s;
    __syncthreads();
    for (int off = 128; off > 0; off >>= 1) {
        if (threadIdx.x < off) red[threadIdx.x] += red[threadIdx.x + off];
        __syncthreads();
    }
    if (threadIdx.x == 0) bsum[blockIdx.x] = red[0];
}

__global__ void k_scanmeta(const int* __restrict__ bsum, int* __restrict__ bpre, int NB,
                           int* __restrict__ row_ptr_last,
                           const int* __restrict__ cls_cnt, int* __restrict__ cls_ptr,
                           float* __restrict__ inv_cnt,
                           const float* __restrict__ mean_sum, float* __restrict__ meanv,
                           int N) {
    __shared__ int lds[256];
    int t = threadIdx.x;
    int v = (t < NB) ? bsum[t] : 0;
    lds[t] = v;
    __syncthreads();
    for (int off = 1; off < 256; off <<= 1) {
        int u = (t >= off) ? lds[t - off] : 0;
        __syncthreads();
        lds[t] += u;
        __syncthreads();
    }
    if (t < NB) bpre[t] = lds[t] - v;          // exclusive block prefix
    if (t == 255) *row_ptr_last = lds[255];    // row_ptr[N] = E
    if (t < NF) meanv[t] = mean_sum[t] * (1.f / (float)N);
    if (t == 0) {
        int s2 = 0;
        for (int c = 0; c < NC; ++c) {
            cls_ptr[c] = s2;
            int cc = cls_cnt[c];
            s2 += cc;
            inv_cnt[c] = 1.f / ((float)cc + 1e-8f);
        }
        cls_ptr[NC] = s2;
    }
}

__global__ void __launch_bounds__(256) k_fillptr(const int* __restrict__ deg_cnt,
                                                 const int* __restrict__ bpre,
                                                 int* __restrict__ row_ptr,
                                                 float* __restrict__ inv_deg, int n4) {
    __shared__ int lds[256];
    int t = threadIdx.x;
    int idx4 = blockIdx.x * 256 + t;
    int4 d = {0, 0, 0, 0};
    if (idx4 < n4) d = ((const int4*)deg_cnt)[idx4];
    int s = d.x + d.y + d.z + d.w;
    lds[t] = s;
    __syncthreads();
    for (int off = 1; off < 256; off <<= 1) {
        int u = (t >= off) ? lds[t - off] : 0;
        __syncthreads();
        lds[t] += u;
        __syncthreads();
    }
    if (idx4 < n4) {
        int base = bpre[blockIdx.x] + lds[t] - s;
        int4 rp;
        rp.x = base;
        rp.y = rp.x + d.x;
        rp.z = rp.y + d.y;
        rp.w = rp.z + d.z;
        ((int4*)row_ptr)[idx4] = rp;
        float4 id;
        id.x = 1.f / (float)(d.x + 1);
        id.y = 1.f / (float)(d.y + 1);
        id.z = 1.f / (float)(d.z + 1);
        id.w = 1.f / (float)(d.w + 1);
        ((float4*)inv_deg)[idx4] = id;
    }
}

// deg_cnt consumed as a countdown here (re-zeroed by next call's memset).
__global__ void k_fill(const int* __restrict__ row, const int* __restrict__ col,
                       const int* __restrict__ row_ptr, int* __restrict__ deg_cnt,
                       int* __restrict__ csr_col, const int* __restrict__ ylab,
                       const int* __restrict__ cls_ptr, int* __restrict__ cls_fill,
                       int* __restrict__ cls_nodes, int N, int E) {
    int stride = gridDim.x * blockDim.x;
    for (int e = blockIdx.x * blockDim.x + threadIdx.x; e < E; e += stride) {
        int r = row[e];
        int d = atomicSub(&deg_cnt[r], 1);
        csr_col[row_ptr[r] + d - 1] = col[e];
    }
    for (int i = blockIdx.x * blockDim.x + threadIdx.x; i < N; i += stride) {
        int lab = ylab[i];
        if (lab >= 0) {
            int pos = cls_ptr[lab] + atomicAdd(&cls_fill[lab], 1);
            cls_nodes[pos] = i;
        }
    }
}

__global__ void k_init(const float* __restrict__ x, const float* __restrict__ meanv,
                       float* __restrict__ vinit, int N) {
    long total = (long)N * NF;
    long stride = (long)gridDim.x * blockDim.x;
    for (long i = blockIdx.x * blockDim.x + threadIdx.x; i < total; i += stride)
        vinit[i] = x[i] - meanv[(int)(i & (NF - 1))];
}

// ---------- per-iteration kernels ----------

// class sums: yTv[c][f] += sum_{i in class c} v[i][f]
// 16 lanes x float4 per row; 4 lane-groups stream 4 nodes in parallel.
__global__ void __launch_bounds__(256) k_accum(const float* __restrict__ v,
                                               const int* __restrict__ cls_ptr,
                                               const int* __restrict__ cls_nodes,
                                               float* __restrict__ yTv) {
    __shared__ float red[4 * NF];
    int c = blockIdx.x;
    int lane = threadIdx.x & 63;
    int w = threadIdx.x >> 6;
    int g = lane >> 4, q = lane & 15;
    int W = blockIdx.y * 4 + w;              // wave id 0..63
    int cs = cls_ptr[c], ce = cls_ptr[c + 1];
    const float4* v4 = (const float4*)v;
    float4 acc = {0.f, 0.f, 0.f, 0.f};
    for (int p = cs + W * 4 + g; p < ce; p += 64 * 4) {
        int node = cls_nodes[p];
        float4 a = v4[(long)node * 16 + q];
        acc.x += a.x; acc.y += a.y; acc.z += a.z; acc.w += a.w;
    }
#pragma unroll
    for (int m = 16; m <= 32; m <<= 1) {
        acc.x += __shfl_xor(acc.x, m);
        acc.y += __shfl_xor(acc.y, m);
        acc.z += __shfl_xor(acc.z, m);
        acc.w += __shfl_xor(acc.w, m);
    }
    if (g == 0) *(float4*)&red[w * NF + q * 4] = acc;
    __syncthreads();
    if (w == 0) {
        float s = red[0 * NF + lane] + red[1 * NF + lane] +
                  red[2 * NF + lane] + red[3 * NF + lane];
        atomicAdd(&yTv[c * NF + lane], s);
    }
}

// v_new[i] = 0.45*inv_deg[i]*(v[i]+sum_nbr v) + 0.05*p2[i] + 0.5*(x[i]-mean)
// Gather: 16 lanes x float4 cover a 256B row; lane-groups g=0..3 walk edge
// sub-streams s+g, s+g+4, ...; unroll x2 -> 8 edges (2KB) in flight per wave.
__global__ void __launch_bounds__(256) k_combine(
        const float* __restrict__ v, float* __restrict__ vn,
        const float* __restrict__ x, const float* __restrict__ meanv,
        const float* __restrict__ inv_deg,
        const int* __restrict__ row_ptr, const int* __restrict__ csr_col,
        const int* __restrict__ ylab, const float* __restrict__ yTv_cur,
        const float* __restrict__ inv_cnt, float* __restrict__ yTv_next_zero, int N) {
    int lane = threadIdx.x & 63;
    int w = threadIdx.x >> 6;
    int i = blockIdx.x * 4 + w;
    if (blockIdx.x == 0) {  // zero next iteration's yTv buffer
        for (int j = threadIdx.x; j < NC * NF; j += 256) yTv_next_zero[j] = 0.f;
    }
    if (i >= N) return;
    int s = row_ptr[i], e = row_ptr[i + 1];
    int g = lane >> 4, q = lane & 15;
    const float4* v4 = (const float4*)v;
    float4 acc0 = {0.f, 0.f, 0.f, 0.f};
    float4 acc1 = {0.f, 0.f, 0.f, 0.f};
    int p = s + g;
    for (; p + 4 < e; p += 8) {
        int c0 = csr_col[p];
        int c1 = csr_col[p + 4];
        float4 a = v4[(long)c0 * 16 + q];
        float4 b = v4[(long)c1 * 16 + q];
        acc0.x += a.x; acc0.y += a.y; acc0.z += a.z; acc0.w += a.w;
        acc1.x += b.x; acc1.y += b.y; acc1.z += b.z; acc1.w += b.w;
    }
    if (p < e) {
        int c0 = csr_col[p];
        float4 a = v4[(long)c0 * 16 + q];
        acc0.x += a.x; acc0.y += a.y; acc0.z += a.z; acc0.w += a.w;
    }
    acc0.x += acc1.x; acc0.y += acc1.y; acc0.z += acc1.z; acc0.w += acc1.w;
#pragma unroll
    for (int m = 16; m <= 32; m <<= 1) {
        acc0.x += __shfl_xor(acc0.x, m);
        acc0.y += __shfl_xor(acc0.y, m);
        acc0.z += __shfl_xor(acc0.z, m);
        acc0.w += __shfl_xor(acc0.w, m);
    }
    int f = q * 4 + g;   // this lane finalizes feature f (permuted within 256B)
    float gsum = (g == 0) ? acc0.x : (g == 1) ? acc0.y : (g == 2) ? acc0.z : acc0.w;
    float selfv = v[(long)i * NF + f];
    float p1 = inv_deg[i] * (gsum + selfv);
    int lab = ylab[i];
    float p2 = (lab >= 0) ? yTv_cur[lab * NF + f] * inv_cnt[lab] : 0.f;
    float base = x[(long)i * NF + f] - meanv[f];
    vn[(long)i * NF + f] = 0.45f * p1 + 0.05f * p2 + 0.5f * base;
}

// out = v @ W + bias (in-place safe: row is in registers before the store)
__global__ void __launch_bounds__(256) k_out(const float* __restrict__ v,
                                             const float* __restrict__ Wm,
                                             const float* __restrict__ bias,
                                             float* __restrict__ out, int N) {
    __shared__ float Wl[NF * NF];
    for (int j = threadIdx.x; j < NF * NF; j += 256) Wl[j] = Wm[j];
    __syncthreads();
    int lane = threadIdx.x & 63;
    int w = threadIdx.x >> 6;
    int i = blockIdx.x * 4 + w;
    if (i >= N) return;
    float vr = v[(long)i * NF + lane];
    float acc = bias[lane];
#pragma unroll
    for (int k = 0; k < NF; ++k)
        acc += __shfl(vr, k, 64) * Wl[k * NF + lane];
    out[(long)i * NF + lane] = acc;
}

// ---------- launcher ----------

extern "C" void kernel_launch(void* const* d_in, const int* in_sizes, int n_in,
                              void* d_out, int out_size, void* d_ws, size_t ws_size,
                              hipStream_t stream) {
    const float* x      = (const float*)d_in[0];
    const float* weight = (const float*)d_in[1];
    const float* bias   = (const float*)d_in[2];
    const int*   row    = (const int*)d_in[3];
    const int*   col    = (const int*)d_in[4];
    const int*   y      = (const int*)d_in[5];
    const int*   mask   = (const int*)d_in[6];
    int N = in_sizes[0] / NF;
    int E = in_sizes[3];
    int n4 = N / 4;                       // N=50000 -> 12500 (divisible)
    int NB = (n4 + 255) / 256;            // 49 blocks (<=256 for meta scan)

    char* ws = (char*)d_ws;
    size_t off = 0;
    auto alloc = [&](size_t bytes) -> void* {
        void* p = ws + off;
        off = (off + bytes + 255) & ~(size_t)255;
        return p;
    };
    float* v0        = (float*)alloc((size_t)N * NF * 4);   // 12.8 MB
    // zero region (one memset per call)
    char*  zbase     = ws + off;
    float* yTv0      = (float*)alloc(NC * NF * 4);
    float* yTv1      = (float*)alloc(NC * NF * 4);
    int*   deg_cnt   = (int*)  alloc((size_t)N * 4);
    int*   cls_cnt   = (int*)  alloc(NC * 4);
    int*   cls_fill  = (int*)  alloc(NC * 4);
    float* mean_sum  = (float*)alloc(NF * 4);
    size_t zbytes = (size_t)((ws + off) - zbase);
    // setup-written, iteration-read
    float* meanv     = (float*)alloc(NF * 4);
    float* inv_deg   = (float*)alloc((size_t)N * 4);
    int*   row_ptr   = (int*)  alloc((size_t)(N + 1) * 4);
    int*   cls_ptr   = (int*)  alloc((NC + 1) * 4);
    float* inv_cnt   = (float*)alloc(NC * 4);
    int*   ylab      = (int*)  alloc((size_t)N * 4);
    int*   cls_nodes = (int*)  alloc((size_t)N * 4);
    int*   bsum      = (int*)  alloc(256 * 4);
    int*   bpre      = (int*)  alloc(256 * 4);
    int*   csr_col   = (int*)  alloc((size_t)E * 4);        // 3.2 MB

    float* vout = (float*)d_out;   // ping-pong partner of v0

    hipMemsetAsync(zbase, 0, zbytes, stream);

    k_deg     <<<1024, 256, 0, stream>>>(row, deg_cnt, E);
    k_node    <<<128, 256, 0, stream>>>(x, y, mask, ylab, cls_cnt, mean_sum, N);
    k_blocksum<<<NB, 256, 0, stream>>>(deg_cnt, bsum, n4);
    k_scanmeta<<<1, 256, 0, stream>>>(bsum, bpre, NB, row_ptr + N,
                                      cls_cnt, cls_ptr, inv_cnt, mean_sum, meanv, N);
    k_fillptr <<<NB, 256, 0, stream>>>(deg_cnt, bpre, row_ptr, inv_deg, n4);
    k_fill    <<<1024, 256, 0, stream>>>(row, col, row_ptr, deg_cnt, csr_col,
                                         ylab, cls_ptr, cls_fill, cls_nodes, N, E);
    k_init    <<<2048, 256, 0, stream>>>(x, meanv, vout, N);  // v_0 = xc in d_out

    int nblk = (N + 3) / 4;
    for (int t = 0; t < 50; ++t) {
        const float* vc = (t & 1) ? v0   : vout;
        float*       vn = (t & 1) ? vout : v0;
        float* yv_cur = (t & 1) ? yTv1 : yTv0;
        float* yv_nxt = (t & 1) ? yTv0 : yTv1;
        k_accum<<<dim3(NC, 16), 256, 0, stream>>>(vc, cls_ptr, cls_nodes, yv_cur);
        k_combine<<<nblk, 256, 0, stream>>>(vc, vn, x, meanv, inv_deg, row_ptr,
                                            csr_col, ylab, yv_cur, inv_cnt, yv_nxt, N);
    }
    // after 50 iters (even count), final v is back in d_out
    k_out<<<nblk, 256, 0, stream>>>(vout, weight, bias, (float*)d_out, N);
}

// Round 4
// 1881.318 us; speedup vs baseline: 1.7716x; 1.1660x over previous
//
#include <hip/hip_runtime.h>

#define NF 64
#define NC 40

typedef _Float16 half1;
typedef _Float16 half4 __attribute__((ext_vector_type(4)));
typedef float    f32x4 __attribute__((ext_vector_type(4)));

// ---------- setup kernels (run once per call) ----------

__global__ void k_deg(const int* __restrict__ row, int* __restrict__ deg_cnt, int E) {
    int stride = gridDim.x * blockDim.x;
    for (int e = blockIdx.x * blockDim.x + threadIdx.x; e < E; e += stride)
        atomicAdd(&deg_cnt[row[e]], 1);
}

__global__ void k_node(const float* __restrict__ x, const int* __restrict__ y,
                       const int* __restrict__ mask, int* __restrict__ ylab,
                       int* __restrict__ cls_cnt, float* __restrict__ mean_sum, int N) {
    __shared__ float lmean[NF];
    __shared__ int   lcls[NC];
    int t = threadIdx.x;
    if (t < NF) lmean[t] = 0.f;
    if (t < NC) lcls[t]  = 0;
    __syncthreads();
    int stride = gridDim.x * blockDim.x;
    float acc = 0.f;
    long total = (long)N * NF;
    for (long i = blockIdx.x * blockDim.x + t; i < total; i += stride)
        acc += x[i];
    atomicAdd(&lmean[t & (NF - 1)], acc);
    for (int i = blockIdx.x * blockDim.x + t; i < N; i += stride) {
        int lab = (mask[i] > 0) ? y[i] : -1;
        ylab[i] = lab;
        if (lab >= 0) atomicAdd(&lcls[lab], 1);
    }
    __syncthreads();
    if (t < NF) atomicAdd(&mean_sum[t], lmean[t]);
    if (t < NC) atomicAdd(&cls_cnt[t], lcls[t]);
}

// hierarchical scan of deg_cnt (N % 4 == 0; N=50000 -> n4=12500)
__global__ void __launch_bounds__(256) k_blocksum(const int* __restrict__ deg_cnt,
                                                  int* __restrict__ bsum, int n4) {
    __shared__ int red[256];
    int idx4 = blockIdx.x * 256 + threadIdx.x;
    int s = 0;
    if (idx4 < n4) {
        int4 d = ((const int4*)deg_cnt)[idx4];
        s = d.x + d.y + d.z + d.w;
    }
    red[threadIdx.x] = s;
    __syncthreads();
    for (int off = 128; off > 0; off >>= 1) {
        if (threadIdx.x < off) red[threadIdx.x] += red[threadIdx.x + off];
        __syncthreads();
    }
    if (threadIdx.x == 0) bsum[blockIdx.x] = red[0];
}

__global__ void k_scanmeta(const int* __restrict__ bsum, int* __restrict__ bpre, int NB,
                           int* __restrict__ row_ptr_last,
                           const int* __restrict__ cls_cnt, int* __restrict__ cls_ptr,
                           float* __restrict__ inv_cnt,
                           const float* __restrict__ mean_sum, float* __restrict__ meanv,
                           int N) {
    __shared__ int lds[256];
    int t = threadIdx.x;
    int v = (t < NB) ? bsum[t] : 0;
    lds[t] = v;
    __syncthreads();
    for (int off = 1; off < 256; off <<= 1) {
        int u = (t >= off) ? lds[t - off] : 0;
        __syncthreads();
        lds[t] += u;
        __syncthreads();
    }
    if (t < NB) bpre[t] = lds[t] - v;
    if (t == 255) *row_ptr_last = lds[255];
    if (t < NF) meanv[t] = mean_sum[t] * (1.f / (float)N);
    if (t == 0) {
        int s2 = 0;
        for (int c = 0; c < NC; ++c) {
            cls_ptr[c] = s2;
            int cc = cls_cnt[c];
            s2 += cc;
            inv_cnt[c] = 1.f / ((float)cc + 1e-8f);
        }
        cls_ptr[NC] = s2;
    }
}

__global__ void __launch_bounds__(256) k_fillptr(const int* __restrict__ deg_cnt,
                                                 const int* __restrict__ bpre,
                                                 int* __restrict__ row_ptr,
                                                 float* __restrict__ inv_deg, int n4) {
    __shared__ int lds[256];
    int t = threadIdx.x;
    int idx4 = blockIdx.x * 256 + t;
    int4 d = {0, 0, 0, 0};
    if (idx4 < n4) d = ((const int4*)deg_cnt)[idx4];
    int s = d.x + d.y + d.z + d.w;
    lds[t] = s;
    __syncthreads();
    for (int off = 1; off < 256; off <<= 1) {
        int u = (t >= off) ? lds[t - off] : 0;
        __syncthreads();
        lds[t] += u;
        __syncthreads();
    }
    if (idx4 < n4) {
        int base = bpre[blockIdx.x] + lds[t] - s;
        int4 rp;
        rp.x = base;
        rp.y = rp.x + d.x;
        rp.z = rp.y + d.y;
        rp.w = rp.z + d.z;
        ((int4*)row_ptr)[idx4] = rp;
        float4 id;
        id.x = 1.f / (float)(d.x + 1);
        id.y = 1.f / (float)(d.y + 1);
        id.z = 1.f / (float)(d.z + 1);
        id.w = 1.f / (float)(d.w + 1);
        ((float4*)inv_deg)[idx4] = id;
    }
}

// deg_cnt consumed as a countdown (re-zeroed by next call's memset).
__global__ void k_fill(const int* __restrict__ row, const int* __restrict__ col,
                       const int* __restrict__ row_ptr, int* __restrict__ deg_cnt,
                       int* __restrict__ csr_col, const int* __restrict__ ylab,
                       const int* __restrict__ cls_ptr, int* __restrict__ cls_fill,
                       int* __restrict__ cls_nodes, int N, int E) {
    int stride = gridDim.x * blockDim.x;
    for (int e = blockIdx.x * blockDim.x + threadIdx.x; e < E; e += stride) {
        int r = row[e];
        int d = atomicSub(&deg_cnt[r], 1);
        csr_col[row_ptr[r] + d - 1] = col[e];
    }
    for (int i = blockIdx.x * blockDim.x + threadIdx.x; i < N; i += stride) {
        int lab = ylab[i];
        if (lab >= 0) {
            int pos = cls_ptr[lab] + atomicAdd(&cls_fill[lab], 1);
            cls_nodes[pos] = i;
        }
    }
}

// v0h = xch = fp16(x - mean); each thread handles one half4 (4 features)
__global__ void k_init(const float* __restrict__ x, const float* __restrict__ meanv,
                       half1* __restrict__ v0h, half1* __restrict__ xch, int N) {
    int total = N * 16;                      // half4 count
    int stride = gridDim.x * blockDim.x;
    const float4* x4 = (const float4*)x;
    const float4* m4 = (const float4*)meanv;
    for (int idx = blockIdx.x * blockDim.x + threadIdx.x; idx < total; idx += stride) {
        float4 xv = x4[idx];
        float4 mv = m4[idx & 15];
        half4 h;
        h.x = (half1)(xv.x - mv.x);
        h.y = (half1)(xv.y - mv.y);
        h.z = (half1)(xv.z - mv.z);
        h.w = (half1)(xv.w - mv.w);
        ((half4*)v0h)[idx] = h;
        ((half4*)xch)[idx] = h;
    }
}

// ---------- per-iteration kernels ----------

// class sums: yTv[c][f] += sum_{i in class c} v[i][f]   (fp16 v, f32 accum)
__global__ void __launch_bounds__(256) k_accum(const half1* __restrict__ v,
                                               const int* __restrict__ cls_ptr,
                                               const int* __restrict__ cls_nodes,
                                               float* __restrict__ yTv) {
    __shared__ float red[4 * NF];
    int c = blockIdx.x;
    int lane = threadIdx.x & 63;
    int w = threadIdx.x >> 6;
    int g = lane >> 4, q = lane & 15;
    int W = blockIdx.y * 4 + w;
    int cs = cls_ptr[c], ce = cls_ptr[c + 1];
    const half4* v4 = (const half4*)v;
    f32x4 acc = {0.f, 0.f, 0.f, 0.f};
    for (int p = cs + W * 4 + g; p < ce; p += 64 * 4) {
        int node = cls_nodes[p];
        acc += __builtin_convertvector(v4[(long)node * 16 + q], f32x4);
    }
#pragma unroll
    for (int m = 16; m <= 32; m <<= 1) {
        acc.x += __shfl_xor(acc.x, m);
        acc.y += __shfl_xor(acc.y, m);
        acc.z += __shfl_xor(acc.z, m);
        acc.w += __shfl_xor(acc.w, m);
    }
    if (g == 0) {
        red[w * NF + q * 4 + 0] = acc.x;
        red[w * NF + q * 4 + 1] = acc.y;
        red[w * NF + q * 4 + 2] = acc.z;
        red[w * NF + q * 4 + 3] = acc.w;
    }
    __syncthreads();
    if (w == 0) {
        float s = red[0 * NF + lane] + red[1 * NF + lane] +
                  red[2 * NF + lane] + red[3 * NF + lane];
        atomicAdd(&yTv[c * NF + lane], s);
    }
}

// v_new[i] = 0.45*inv_deg[i]*(v[i]+sum_nbr v) + 0.05*p2[i] + 0.5*xc[i]
// fp16 v rows (128B): 16 lanes x half4; 4 lane-groups x 4 streams
// -> 16 edges (2KB) in flight per wave. f32 accumulation throughout.
__global__ void __launch_bounds__(256) k_combine(
        const half1* __restrict__ v, half1* __restrict__ vn,
        const half1* __restrict__ xch, const float* __restrict__ inv_deg,
        const int* __restrict__ row_ptr, const int* __restrict__ csr_col,
        const int* __restrict__ ylab, const float* __restrict__ yTv_cur,
        const float* __restrict__ inv_cnt, float* __restrict__ yTv_next_zero, int N) {
    int lane = threadIdx.x & 63;
    int w = threadIdx.x >> 6;
    int i = blockIdx.x * 4 + w;
    if (blockIdx.x == 0) {  // zero next iteration's yTv buffer
        for (int j = threadIdx.x; j < NC * NF; j += 256) yTv_next_zero[j] = 0.f;
    }
    if (i >= N) return;
    int s = row_ptr[i], e = row_ptr[i + 1];
    int g = lane >> 4, q = lane & 15;
    const half4* v4 = (const half4*)v;
    f32x4 a0 = {0.f, 0.f, 0.f, 0.f};
    f32x4 a1 = {0.f, 0.f, 0.f, 0.f};
    f32x4 a2 = {0.f, 0.f, 0.f, 0.f};
    f32x4 a3 = {0.f, 0.f, 0.f, 0.f};
    int p = s + g;
    for (; p + 12 < e; p += 16) {
        int c0 = csr_col[p];
        int c1 = csr_col[p + 4];
        int c2 = csr_col[p + 8];
        int c3 = csr_col[p + 12];
        half4 h0 = v4[(long)c0 * 16 + q];
        half4 h1 = v4[(long)c1 * 16 + q];
        half4 h2 = v4[(long)c2 * 16 + q];
        half4 h3 = v4[(long)c3 * 16 + q];
        a0 += __builtin_convertvector(h0, f32x4);
        a1 += __builtin_convertvector(h1, f32x4);
        a2 += __builtin_convertvector(h2, f32x4);
        a3 += __builtin_convertvector(h3, f32x4);
    }
    for (; p < e; p += 4) {
        int c0 = csr_col[p];
        a0 += __builtin_convertvector(v4[(long)c0 * 16 + q], f32x4);
    }
    a0 += a1 + a2 + a3;
#pragma unroll
    for (int m = 16; m <= 32; m <<= 1) {
        a0.x += __shfl_xor(a0.x, m);
        a0.y += __shfl_xor(a0.y, m);
        a0.z += __shfl_xor(a0.z, m);
        a0.w += __shfl_xor(a0.w, m);
    }
    int f = q * 4 + g;   // this lane finalizes feature f
    float gsum = (g == 0) ? a0.x : (g == 1) ? a0.y : (g == 2) ? a0.z : a0.w;
    float selfv = (float)v[(long)i * NF + f];
    float p1 = inv_deg[i] * (gsum + selfv);
    int lab = ylab[i];
    float p2 = (lab >= 0) ? yTv_cur[lab * NF + f] * inv_cnt[lab] : 0.f;
    float base = (float)xch[(long)i * NF + f];
    vn[(long)i * NF + f] = (half1)(0.45f * p1 + 0.05f * p2 + 0.5f * base);
}

// out = v @ W + bias  (reads fp16 v from ws, writes f32 to d_out — no overlap)
__global__ void __launch_bounds__(256) k_out(const half1* __restrict__ v,
                                             const float* __restrict__ Wm,
                                             const float* __restrict__ bias,
                                             float* __restrict__ out, int N) {
    __shared__ float Wl[NF * NF];
    for (int j = threadIdx.x; j < NF * NF; j += 256) Wl[j] = Wm[j];
    __syncthreads();
    int lane = threadIdx.x & 63;
    int w = threadIdx.x >> 6;
    int i = blockIdx.x * 4 + w;
    if (i >= N) return;
    float vr = (float)v[(long)i * NF + lane];
    float acc = bias[lane];
#pragma unroll
    for (int k = 0; k < NF; ++k)
        acc += __shfl(vr, k, 64) * Wl[k * NF + lane];
    out[(long)i * NF + lane] = acc;
}

// ---------- launcher ----------

extern "C" void kernel_launch(void* const* d_in, const int* in_sizes, int n_in,
                              void* d_out, int out_size, void* d_ws, size_t ws_size,
                              hipStream_t stream) {
    const float* x      = (const float*)d_in[0];
    const float* weight = (const float*)d_in[1];
    const float* bias   = (const float*)d_in[2];
    const int*   row    = (const int*)d_in[3];
    const int*   col    = (const int*)d_in[4];
    const int*   y      = (const int*)d_in[5];
    const int*   mask   = (const int*)d_in[6];
    int N = in_sizes[0] / NF;
    int E = in_sizes[3];
    int n4 = N / 4;
    int NB = (n4 + 255) / 256;

    // ws (~17 MB): fp16 v ping-pong + CSR + small arrays.
    // xc (fp16, 6.4 MB) lives in d_out — read-only during the loop; k_out
    // overwrites d_out only after every k_combine has finished.
    char* ws = (char*)d_ws;
    size_t off = 0;
    auto alloc = [&](size_t bytes) -> void* {
        void* p = ws + off;
        off = (off + bytes + 255) & ~(size_t)255;
        return p;
    };
    half1* v0h       = (half1*)alloc((size_t)N * NF * 2);   // 6.4 MB
    half1* v1h       = (half1*)alloc((size_t)N * NF * 2);   // 6.4 MB
    // zero region (one memset per call)
    char*  zbase     = ws + off;
    float* yTv0      = (float*)alloc(NC * NF * 4);
    float* yTv1      = (float*)alloc(NC * NF * 4);
    int*   deg_cnt   = (int*)  alloc((size_t)N * 4);
    int*   cls_cnt   = (int*)  alloc(NC * 4);
    int*   cls_fill  = (int*)  alloc(NC * 4);
    float* mean_sum  = (float*)alloc(NF * 4);
    size_t zbytes = (size_t)((ws + off) - zbase);
    // setup-written, iteration-read
    float* meanv     = (float*)alloc(NF * 4);
    float* inv_deg   = (float*)alloc((size_t)N * 4);
    int*   row_ptr   = (int*)  alloc((size_t)(N + 1) * 4);
    int*   cls_ptr   = (int*)  alloc((NC + 1) * 4);
    float* inv_cnt   = (float*)alloc(NC * 4);
    int*   ylab      = (int*)  alloc((size_t)N * 4);
    int*   cls_nodes = (int*)  alloc((size_t)N * 4);
    int*   bsum      = (int*)  alloc(256 * 4);
    int*   bpre      = (int*)  alloc(256 * 4);
    int*   csr_col   = (int*)  alloc((size_t)E * 4);        // 3.2 MB

    half1* xch = (half1*)d_out;

    hipMemsetAsync(zbase, 0, zbytes, stream);

    k_deg     <<<2048, 256, 0, stream>>>(row, deg_cnt, E);
    k_node    <<<128, 256, 0, stream>>>(x, y, mask, ylab, cls_cnt, mean_sum, N);
    k_blocksum<<<NB, 256, 0, stream>>>(deg_cnt, bsum, n4);
    k_scanmeta<<<1, 256, 0, stream>>>(bsum, bpre, NB, row_ptr + N,
                                      cls_cnt, cls_ptr, inv_cnt, mean_sum, meanv, N);
    k_fillptr <<<NB, 256, 0, stream>>>(deg_cnt, bpre, row_ptr, inv_deg, n4);
    k_fill    <<<2048, 256, 0, stream>>>(row, col, row_ptr, deg_cnt, csr_col,
                                         ylab, cls_ptr, cls_fill, cls_nodes, N, E);
    k_init    <<<1024, 256, 0, stream>>>(x, meanv, v0h, xch, N);

    int nblk = (N + 3) / 4;
    for (int t = 0; t < 50; ++t) {
        const half1* vc = (t & 1) ? v1h : v0h;
        half1*       vn = (t & 1) ? v0h : v1h;
        float* yv_cur = (t & 1) ? yTv1 : yTv0;
        float* yv_nxt = (t & 1) ? yTv0 : yTv1;
        k_accum<<<dim3(NC, 16), 256, 0, stream>>>(vc, cls_ptr, cls_nodes, yv_cur);
        k_combine<<<nblk, 256, 0, stream>>>(vc, vn, xch, inv_deg, row_ptr,
                                            csr_col, ylab, yv_cur, inv_cnt, yv_nxt, N);
    }
    // 50 iters (even): final v in v0h
    k_out<<<nblk, 256, 0, stream>>>(v0h, weight, bias, (float*)d_out, N);
}

// Round 5
// 1551.121 us; speedup vs baseline: 2.1488x; 1.2129x over previous
//
#include <hip/hip_runtime.h>

#define NF 64
#define NC 40

typedef _Float16 half1;
typedef _Float16 half4 __attribute__((ext_vector_type(4)));
typedef _Float16 half8 __attribute__((ext_vector_type(8)));
typedef float    f32x4 __attribute__((ext_vector_type(4)));
typedef float    f32x8 __attribute__((ext_vector_type(8)));

// ---------- setup kernels (run once per call) ----------

__global__ void k_deg(const int* __restrict__ row, int* __restrict__ deg_cnt, int E) {
    int stride = gridDim.x * blockDim.x;
    for (int e = blockIdx.x * blockDim.x + threadIdx.x; e < E; e += stride)
        atomicAdd(&deg_cnt[row[e]], 1);
}

__global__ void k_node(const float* __restrict__ x, const int* __restrict__ y,
                       const int* __restrict__ mask, int* __restrict__ ylab,
                       int* __restrict__ cls_cnt, float* __restrict__ mean_sum, int N) {
    __shared__ float lmean[NF];
    __shared__ int   lcls[NC];
    int t = threadIdx.x;
    if (t < NF) lmean[t] = 0.f;
    if (t < NC) lcls[t]  = 0;
    __syncthreads();
    int stride = gridDim.x * blockDim.x;
    // float4 column sums of x; (stride*4) keeps each thread on the same 4 columns
    const float4* x4 = (const float4*)x;
    int total4 = N * 16;
    f32x4 acc = {0.f, 0.f, 0.f, 0.f};
    for (int i = blockIdx.x * blockDim.x + t; i < total4; i += stride) {
        float4 v = x4[i];
        acc.x += v.x; acc.y += v.y; acc.z += v.z; acc.w += v.w;
    }
    int cbase = (t & 15) * 4;
    atomicAdd(&lmean[cbase + 0], acc.x);
    atomicAdd(&lmean[cbase + 1], acc.y);
    atomicAdd(&lmean[cbase + 2], acc.z);
    atomicAdd(&lmean[cbase + 3], acc.w);
    for (int i = blockIdx.x * blockDim.x + t; i < N; i += stride) {
        int lab = (mask[i] > 0) ? y[i] : -1;
        ylab[i] = lab;
        if (lab >= 0) atomicAdd(&lcls[lab], 1);
    }
    __syncthreads();
    if (t < NF) atomicAdd(&mean_sum[t], lmean[t]);
    if (t < NC) atomicAdd(&cls_cnt[t], lcls[t]);
}

// hierarchical scan of deg_cnt (N % 4 == 0; N=50000 -> n4=12500)
__global__ void __launch_bounds__(256) k_blocksum(const int* __restrict__ deg_cnt,
                                                  int* __restrict__ bsum, int n4) {
    __shared__ int red[256];
    int idx4 = blockIdx.x * 256 + threadIdx.x;
    int s = 0;
    if (idx4 < n4) {
        int4 d = ((const int4*)deg_cnt)[idx4];
        s = d.x + d.y + d.z + d.w;
    }
    red[threadIdx.x] = s;
    __syncthreads();
    for (int off = 128; off > 0; off >>= 1) {
        if (threadIdx.x < off) red[threadIdx.x] += red[threadIdx.x + off];
        __syncthreads();
    }
    if (threadIdx.x == 0) bsum[blockIdx.x] = red[0];
}

__global__ void k_scanmeta(const int* __restrict__ bsum, int* __restrict__ bpre, int NB,
                           int* __restrict__ row_ptr_last,
                           const int* __restrict__ cls_cnt, int* __restrict__ cls_ptr,
                           float* __restrict__ inv_cnt,
                           const float* __restrict__ mean_sum, float* __restrict__ meanv,
                           int N) {
    __shared__ int lds[256];
    int t = threadIdx.x;
    int v = (t < NB) ? bsum[t] : 0;
    lds[t] = v;
    __syncthreads();
    for (int off = 1; off < 256; off <<= 1) {
        int u = (t >= off) ? lds[t - off] : 0;
        __syncthreads();
        lds[t] += u;
        __syncthreads();
    }
    if (t < NB) bpre[t] = lds[t] - v;
    if (t == 255) *row_ptr_last = lds[255];
    if (t < NF) meanv[t] = mean_sum[t] * (1.f / (float)N);
    if (t == 0) {
        int s2 = 0;
        for (int c = 0; c < NC; ++c) {
            cls_ptr[c] = s2;
            int cc = cls_cnt[c];
            s2 += cc;
            inv_cnt[c] = 1.f / ((float)cc + 1e-8f);
        }
        cls_ptr[NC] = s2;
    }
}

__global__ void __launch_bounds__(256) k_fillptr(const int* __restrict__ deg_cnt,
                                                 const int* __restrict__ bpre,
                                                 int* __restrict__ row_ptr,
                                                 float* __restrict__ inv_deg, int n4) {
    __shared__ int lds[256];
    int t = threadIdx.x;
    int idx4 = blockIdx.x * 256 + t;
    int4 d = {0, 0, 0, 0};
    if (idx4 < n4) d = ((const int4*)deg_cnt)[idx4];
    int s = d.x + d.y + d.z + d.w;
    lds[t] = s;
    __syncthreads();
    for (int off = 1; off < 256; off <<= 1) {
        int u = (t >= off) ? lds[t - off] : 0;
        __syncthreads();
        lds[t] += u;
        __syncthreads();
    }
    if (idx4 < n4) {
        int base = bpre[blockIdx.x] + lds[t] - s;
        int4 rp;
        rp.x = base;
        rp.y = rp.x + d.x;
        rp.z = rp.y + d.y;
        rp.w = rp.z + d.z;
        ((int4*)row_ptr)[idx4] = rp;
        float4 id;
        id.x = 1.f / (float)(d.x + 1);
        id.y = 1.f / (float)(d.y + 1);
        id.z = 1.f / (float)(d.z + 1);
        id.w = 1.f / (float)(d.w + 1);
        ((float4*)inv_deg)[idx4] = id;
    }
}

// deg_cnt consumed as a countdown (re-zeroed by next call's memset).
__global__ void k_fill(const int* __restrict__ row, const int* __restrict__ col,
                       const int* __restrict__ row_ptr, int* __restrict__ deg_cnt,
                       int* __restrict__ csr_col, const int* __restrict__ ylab,
                       const int* __restrict__ cls_ptr, int* __restrict__ cls_fill,
                       int* __restrict__ cls_nodes, int N, int E) {
    int stride = gridDim.x * blockDim.x;
    for (int e = blockIdx.x * blockDim.x + threadIdx.x; e < E; e += stride) {
        int r = row[e];
        int d = atomicSub(&deg_cnt[r], 1);
        csr_col[row_ptr[r] + d - 1] = col[e];
    }
    for (int i = blockIdx.x * blockDim.x + threadIdx.x; i < N; i += stride) {
        int lab = ylab[i];
        if (lab >= 0) {
            int pos = cls_ptr[lab] + atomicAdd(&cls_fill[lab], 1);
            cls_nodes[pos] = i;
        }
    }
}

// v0h = xch = fp16(x - mean)
__global__ void k_init(const float* __restrict__ x, const float* __restrict__ meanv,
                       half1* __restrict__ v0h, half1* __restrict__ xch, int N) {
    int total = N * 16;                      // half4 count
    int stride = gridDim.x * blockDim.x;
    const float4* x4 = (const float4*)x;
    const float4* m4 = (const float4*)meanv;
    for (int idx = blockIdx.x * blockDim.x + threadIdx.x; idx < total; idx += stride) {
        float4 xv = x4[idx];
        float4 mv = m4[idx & 15];
        half4 h;
        h.x = (half1)(xv.x - mv.x);
        h.y = (half1)(xv.y - mv.y);
        h.z = (half1)(xv.z - mv.z);
        h.w = (half1)(xv.w - mv.w);
        ((half4*)v0h)[idx] = h;
        ((half4*)xch)[idx] = h;
    }
}

// seed yTv[0] = Y^T v_0  (runs once; loop iterations produce yTv in k_combine)
__global__ void __launch_bounds__(256) k_accum(const half1* __restrict__ v,
                                               const int* __restrict__ cls_ptr,
                                               const int* __restrict__ cls_nodes,
                                               float* __restrict__ yTv) {
    __shared__ float red[4 * NF];
    int c = blockIdx.x;
    int lane = threadIdx.x & 63;
    int w = threadIdx.x >> 6;
    int g = lane >> 4, q = lane & 15;
    int W = blockIdx.y * 4 + w;
    int cs = cls_ptr[c], ce = cls_ptr[c + 1];
    const half4* v4 = (const half4*)v;
    f32x4 acc = {0.f, 0.f, 0.f, 0.f};
    for (int p = cs + W * 4 + g; p < ce; p += 64 * 4) {
        int node = cls_nodes[p];
        acc += __builtin_convertvector(v4[(long)node * 16 + q], f32x4);
    }
#pragma unroll
    for (int m = 16; m <= 32; m <<= 1) {
        acc.x += __shfl_xor(acc.x, m);
        acc.y += __shfl_xor(acc.y, m);
        acc.z += __shfl_xor(acc.z, m);
        acc.w += __shfl_xor(acc.w, m);
    }
    if (g == 0) {
        red[w * NF + q * 4 + 0] = acc.x;
        red[w * NF + q * 4 + 1] = acc.y;
        red[w * NF + q * 4 + 2] = acc.z;
        red[w * NF + q * 4 + 3] = acc.w;
    }
    __syncthreads();
    if (w == 0) {
        float s = red[0 * NF + lane] + red[1 * NF + lane] +
                  red[2 * NF + lane] + red[3 * NF + lane];
        atomicAdd(&yTv[c * NF + lane], s);
    }
}

// ---------- the per-iteration kernel ----------
// v_new[i] = 0.45*inv_deg[i]*(v[i]+sum_nbr v) + 0.05*p2[i] + 0.5*xc[i]
// Gather: 8 lanes x half8 (16B/lane) per row; 8 edge streams x unroll 2
// -> 16 edges (2KB) in flight per wave. f32 accumulation.
// Fused: labeled nodes atomically accumulate v_new into yv_acc (next iter's
// yTv); block 0 zeroes yv_zero (the buffer for iter t+2).
__global__ void __launch_bounds__(256) k_combine(
        const half1* __restrict__ v, half1* __restrict__ vn,
        const half1* __restrict__ xch, const float* __restrict__ inv_deg,
        const int* __restrict__ row_ptr, const int* __restrict__ csr_col,
        const int* __restrict__ ylab, const float* __restrict__ yv_cur,
        const float* __restrict__ inv_cnt, float* __restrict__ yv_acc,
        float* __restrict__ yv_zero, int N) {
    int lane = threadIdx.x & 63;
    int w = threadIdx.x >> 6;
    int i = blockIdx.x * 4 + w;
    if (blockIdx.x == 0) {
        for (int j = threadIdx.x; j < NC * NF; j += 256) yv_zero[j] = 0.f;
    }
    if (i >= N) return;
    int s = row_ptr[i], e = row_ptr[i + 1];
    int g = lane >> 3, q = lane & 7;         // 8 groups x 8 lanes
    const half8* v8 = (const half8*)v;
    f32x8 a0 = {0.f, 0.f, 0.f, 0.f, 0.f, 0.f, 0.f, 0.f};
    f32x8 a1 = {0.f, 0.f, 0.f, 0.f, 0.f, 0.f, 0.f, 0.f};
    int p = s + g;
    for (; p + 8 < e; p += 16) {
        int c0 = csr_col[p];
        int c1 = csr_col[p + 8];
        half8 h0 = v8[(long)c0 * 8 + q];
        half8 h1 = v8[(long)c1 * 8 + q];
        a0 += __builtin_convertvector(h0, f32x8);
        a1 += __builtin_convertvector(h1, f32x8);
    }
    if (p < e) {
        int c0 = csr_col[p];
        a0 += __builtin_convertvector(v8[(long)c0 * 8 + q], f32x8);
    }
    a0 += a1;
    // sum across the 8 groups (lanes differing in bits 3..5)
#pragma unroll
    for (int m = 8; m <= 32; m <<= 1) {
#pragma unroll
        for (int j = 0; j < 8; ++j)
            a0[j] += __shfl_xor(a0[j], m);
    }
    int f = q * 8 + g;                        // this lane finalizes feature f
    float gsum = a0[g];
    float selfv = (float)v[(long)i * NF + f];
    float p1 = inv_deg[i] * (gsum + selfv);
    int lab = ylab[i];
    float p2 = (lab >= 0) ? yv_cur[lab * NF + f] * inv_cnt[lab] : 0.f;
    float base = (float)xch[(long)i * NF + f];
    float res = 0.45f * p1 + 0.05f * p2 + 0.5f * base;
    vn[(long)i * NF + f] = (half1)res;
    if (lab >= 0) atomicAdd(&yv_acc[lab * NF + f], res);
}

// out = v @ W + bias  (reads fp16 v from ws, writes f32 to d_out)
__global__ void __launch_bounds__(256) k_out(const half1* __restrict__ v,
                                             const float* __restrict__ Wm,
                                             const float* __restrict__ bias,
                                             float* __restrict__ out, int N) {
    __shared__ float Wl[NF * NF];
    for (int j = threadIdx.x; j < NF * NF; j += 256) Wl[j] = Wm[j];
    __syncthreads();
    int lane = threadIdx.x & 63;
    int w = threadIdx.x >> 6;
    int i = blockIdx.x * 4 + w;
    if (i >= N) return;
    float vr = (float)v[(long)i * NF + lane];
    float acc = bias[lane];
#pragma unroll
    for (int k = 0; k < NF; ++k)
        acc += __shfl(vr, k, 64) * Wl[k * NF + lane];
    out[(long)i * NF + lane] = acc;
}

// ---------- launcher ----------

extern "C" void kernel_launch(void* const* d_in, const int* in_sizes, int n_in,
                              void* d_out, int out_size, void* d_ws, size_t ws_size,
                              hipStream_t stream) {
    const float* x      = (const float*)d_in[0];
    const float* weight = (const float*)d_in[1];
    const float* bias   = (const float*)d_in[2];
    const int*   row    = (const int*)d_in[3];
    const int*   col    = (const int*)d_in[4];
    const int*   y      = (const int*)d_in[5];
    const int*   mask   = (const int*)d_in[6];
    int N = in_sizes[0] / NF;
    int E = in_sizes[3];
    int n4 = N / 4;
    int NB = (n4 + 255) / 256;

    // ws (~17 MB). xc (fp16, 6.4 MB) lives in d_out — read-only during the
    // loop; k_out overwrites d_out only after the last k_combine finished.
    char* ws = (char*)d_ws;
    size_t off = 0;
    auto alloc = [&](size_t bytes) -> void* {
        void* p = ws + off;
        off = (off + bytes + 255) & ~(size_t)255;
        return p;
    };
    half1* v0h       = (half1*)alloc((size_t)N * NF * 2);   // 6.4 MB
    half1* v1h       = (half1*)alloc((size_t)N * NF * 2);   // 6.4 MB
    // zero region (one memset per call)
    char*  zbase     = ws + off;
    float* yv[3];
    yv[0]            = (float*)alloc(NC * NF * 4);
    yv[1]            = (float*)alloc(NC * NF * 4);
    yv[2]            = (float*)alloc(NC * NF * 4);
    int*   deg_cnt   = (int*)  alloc((size_t)N * 4);
    int*   cls_cnt   = (int*)  alloc(NC * 4);
    int*   cls_fill  = (int*)  alloc(NC * 4);
    float* mean_sum  = (float*)alloc(NF * 4);
    size_t zbytes = (size_t)((ws + off) - zbase);
    // setup-written, iteration-read
    float* meanv     = (float*)alloc(NF * 4);
    float* inv_deg   = (float*)alloc((size_t)N * 4);
    int*   row_ptr   = (int*)  alloc((size_t)(N + 1) * 4);
    int*   cls_ptr   = (int*)  alloc((NC + 1) * 4);
    float* inv_cnt   = (float*)alloc(NC * 4);
    int*   ylab      = (int*)  alloc((size_t)N * 4);
    int*   cls_nodes = (int*)  alloc((size_t)N * 4);
    int*   bsum      = (int*)  alloc(256 * 4);
    int*   bpre      = (int*)  alloc(256 * 4);
    int*   csr_col   = (int*)  alloc((size_t)E * 4);        // 3.2 MB

    half1* xch = (half1*)d_out;

    hipMemsetAsync(zbase, 0, zbytes, stream);

    k_deg     <<<2048, 256, 0, stream>>>(row, deg_cnt, E);
    k_node    <<<128, 256, 0, stream>>>(x, y, mask, ylab, cls_cnt, mean_sum, N);
    k_blocksum<<<NB, 256, 0, stream>>>(deg_cnt, bsum, n4);
    k_scanmeta<<<1, 256, 0, stream>>>(bsum, bpre, NB, row_ptr + N,
                                      cls_cnt, cls_ptr, inv_cnt, mean_sum, meanv, N);
    k_fillptr <<<NB, 256, 0, stream>>>(deg_cnt, bpre, row_ptr, inv_deg, n4);
    k_fill    <<<2048, 256, 0, stream>>>(row, col, row_ptr, deg_cnt, csr_col,
                                         ylab, cls_ptr, cls_fill, cls_nodes, N, E);
    k_init    <<<1024, 256, 0, stream>>>(x, meanv, v0h, xch, N);
    // seed yv[0] = Y^T v_0
    k_accum   <<<dim3(NC, 16), 256, 0, stream>>>(v0h, cls_ptr, cls_nodes, yv[0]);

    int nblk = (N + 3) / 4;
    for (int t = 0; t < 50; ++t) {
        const half1* vc = (t & 1) ? v1h : v0h;
        half1*       vn = (t & 1) ? v0h : v1h;
        k_combine<<<nblk, 256, 0, stream>>>(vc, vn, xch, inv_deg, row_ptr, csr_col,
                                            ylab, yv[t % 3], inv_cnt,
                                            yv[(t + 1) % 3], yv[(t + 2) % 3], N);
    }
    // 50 iters (even): final v in v0h
    k_out<<<nblk, 256, 0, stream>>>(v0h, weight, bias, (float*)d_out, N);
}